// Round 1
// baseline (638.380 us; speedup 1.0000x reference)
//
#include <hip/hip_runtime.h>

#define N_NODES 50000
#define N_EDGES 800000
#define N_GRAPHS 512
#define DIM 128

// ---------------- graph preprocessing ----------------

__global__ void init_deg_k(int* deg, int n) {
    int i = blockIdx.x * blockDim.x + threadIdx.x;
    if (i < n) deg[i] = 1;  // self-loop
}

__global__ void count_k(const int* __restrict__ dst, int* deg, int e) {
    int i = blockIdx.x * blockDim.x + threadIdx.x;
    if (i < e) atomicAdd(&deg[dst[i]], 1);
}

__global__ void dis_k(const int* __restrict__ deg, float* dis, int n) {
    int i = blockIdx.x * blockDim.x + threadIdx.x;
    if (i < n) dis[i] = rsqrtf((float)deg[i]);   // deg >= 1 always (self-loops)
}

// single-block exclusive scan over n<=50176 elements (1024 threads x 49)
__global__ void scan_k(const int* __restrict__ deg, int* row_ptr, int n) {
    __shared__ int sums[1024];
    int t = threadIdx.x;
    const int per = (n + 1023) / 1024;
    int base = t * per;
    int s = 0;
    for (int i = 0; i < per; i++) {
        int idx = base + i;
        if (idx < n) s += deg[idx];
    }
    sums[t] = s;
    __syncthreads();
    for (int off = 1; off < 1024; off <<= 1) {
        int v = sums[t];
        int add = (t >= off) ? sums[t - off] : 0;
        __syncthreads();
        sums[t] = v + add;
        __syncthreads();
    }
    int run = (t == 0) ? 0 : sums[t - 1];
    for (int i = 0; i < per; i++) {
        int idx = base + i;
        if (idx < n) { row_ptr[idx] = run; run += deg[idx]; }
    }
    if (t == 1023) row_ptr[n] = run;  // thread 1023's range is fully >= n, run == total
}

__global__ void cursor_k(const int* __restrict__ row_ptr, int* cursor, int n) {
    int i = blockIdx.x * blockDim.x + threadIdx.x;
    if (i < n) cursor[i] = row_ptr[i];
}

__global__ void fill_k(const int* __restrict__ src, const int* __restrict__ dst,
                       const float* __restrict__ dis, int* cursor,
                       int* col, float* wgt, int e, int n) {
    int i = blockIdx.x * blockDim.x + threadIdx.x;
    if (i < e) {
        int s = src[i], d = dst[i];
        int pos = atomicAdd(&cursor[d], 1);
        col[pos] = s;
        wgt[pos] = dis[s] * dis[d];
    } else if (i < e + n) {
        int v = i - e;
        int pos = atomicAdd(&cursor[v], 1);
        col[pos] = v;
        wgt[pos] = dis[v] * dis[v];
    }
}

// ---------------- dense GEMM: H[n x 128] = X[n x 128] @ W[128 x 128] ----------------
// 32 rows/block, 256 threads, 4x4 register tile/thread.
// W staged in LDS in two 64-row halves (32 KB each) to stay under 64 KB static LDS.

#define GEMM_ROWS 32

__global__ __launch_bounds__(256) void gemm_k(const float* __restrict__ X,
                                              const float* __restrict__ W,
                                              float* __restrict__ H, int n) {
    __shared__ float Ws[64 * 128];          // 32 KB (half of W's K range)
    __shared__ float Xs[GEMM_ROWS * 128];   // 16 KB

    int t = threadIdx.x;
    int row0 = blockIdx.x * GEMM_ROWS;

    // stage X tile (float4, coalesced)
    for (int i = t; i < GEMM_ROWS * 32; i += 256) {
        int r = i >> 5, q = i & 31;
        float4 v = make_float4(0.f, 0.f, 0.f, 0.f);
        if (row0 + r < n) v = ((const float4*)X)[(size_t)(row0 + r) * 32 + q];
        ((float4*)Xs)[i] = v;
    }

    int tc = t & 31, tr = t >> 5;   // col-tile 0..31, row-tile 0..7
    int j0 = tc * 4, r0 = tr * 4;
    float acc[4][4];
#pragma unroll
    for (int a = 0; a < 4; a++)
#pragma unroll
        for (int b = 0; b < 4; b++) acc[a][b] = 0.f;

    for (int kp = 0; kp < 2; kp++) {
        int k0 = kp * 64;
        __syncthreads();
        for (int i = t; i < 64 * 32; i += 256)
            ((float4*)Ws)[i] = ((const float4*)W)[k0 * 32 + i];
        __syncthreads();
#pragma unroll 4
        for (int k = 0; k < 64; k++) {
            float4 wv = *(const float4*)(Ws + k * 128 + j0);  // ds_read_b128, stride-1
#pragma unroll
            for (int a = 0; a < 4; a++) {
                float xv = Xs[(r0 + a) * 128 + k0 + k];       // wave-broadcast
                acc[a][0] += xv * wv.x;
                acc[a][1] += xv * wv.y;
                acc[a][2] += xv * wv.z;
                acc[a][3] += xv * wv.w;
            }
        }
    }

#pragma unroll
    for (int a = 0; a < 4; a++) {
        int row = row0 + r0 + a;
        if (row < n)
            *(float4*)(H + (size_t)row * 128 + j0) =
                make_float4(acc[a][0], acc[a][1], acc[a][2], acc[a][3]);
    }
}

// ---------------- CSR aggregation + bias + ReLU ----------------
// one wave per node, float2 per lane -> one coalesced 512B row read per edge

__global__ __launch_bounds__(256) void agg_k(const float* __restrict__ H,
                                             const int* __restrict__ row_ptr,
                                             const int* __restrict__ col,
                                             const float* __restrict__ wgt,
                                             const float* __restrict__ bias,
                                             float* __restrict__ Out, int n) {
    int node = blockIdx.x * 4 + (threadIdx.x >> 6);
    int lane = threadIdx.x & 63;
    if (node >= n) return;
    int beg = row_ptr[node], end = row_ptr[node + 1];
    float a0 = 0.f, a1 = 0.f;
    for (int e = beg; e < end; e++) {
        int c = col[e];
        float w = wgt[e];
        float2 hv = *(const float2*)(H + (size_t)c * DIM + lane * 2);
        a0 += w * hv.x;
        a1 += w * hv.y;
    }
    a0 += bias[lane * 2];
    a1 += bias[lane * 2 + 1];
    a0 = fmaxf(a0, 0.f);
    a1 = fmaxf(a1, 0.f);
    *(float2*)(Out + (size_t)node * DIM + lane * 2) = make_float2(a0, a1);
}

// ---------------- global add pool (batch_vec sorted) ----------------
// block = 128 threads (one per column), 64 consecutive nodes per block,
// run-length accumulate, one atomic per graph-run per column.

__global__ void pool_k(const float* __restrict__ H, const int* __restrict__ batch,
                       float* Out, int n) {
    int d = threadIdx.x;
    int n0 = blockIdx.x * 64;
    int gcur = -1;
    float s = 0.f;
    for (int i = 0; i < 64; i++) {
        int node = n0 + i;
        if (node >= n) break;
        int g = batch[node];
        if (g != gcur) {
            if (gcur >= 0) atomicAdd(&Out[gcur * DIM + d], s);
            gcur = g;
            s = 0.f;
        }
        s += H[(size_t)node * DIM + d];
    }
    if (gcur >= 0) atomicAdd(&Out[gcur * DIM + d], s);
}

// ---------------- launch ----------------

extern "C" void kernel_launch(void* const* d_in, const int* in_sizes, int n_in,
                              void* d_out, int out_size, void* d_ws, size_t ws_size,
                              hipStream_t stream) {
    const float* x  = (const float*)d_in[0];
    const float* W1 = (const float*)d_in[1];
    const float* b1 = (const float*)d_in[2];
    const float* W2 = (const float*)d_in[3];
    const float* b2 = (const float*)d_in[4];
    const float* W3 = (const float*)d_in[5];
    const float* b3 = (const float*)d_in[6];
    const int*   ei = (const int*)d_in[7];     // [2, E] flat
    const int*   bv = (const int*)d_in[8];     // [N], sorted
    float* out = (float*)d_out;

    const int N = N_NODES, E = N_EDGES;

    char* p = (char*)d_ws;
    auto alloc = [&](size_t bytes) -> void* {
        void* r = (void*)p;
        p += (bytes + 255) & ~(size_t)255;
        return r;
    };
    int*   deg     = (int*)alloc((size_t)N * 4);
    int*   row_ptr = (int*)alloc((size_t)(N + 1) * 4);
    int*   cursor  = (int*)alloc((size_t)N * 4);
    float* dis     = (float*)alloc((size_t)N * 4);
    int*   col     = (int*)alloc((size_t)(E + N) * 4);
    float* wgt     = (float*)alloc((size_t)(E + N) * 4);
    float* B1      = (float*)alloc((size_t)N * DIM * 4);
    float* B2      = (float*)alloc((size_t)N * DIM * 4);

    const int* src = ei;
    const int* dst = ei + E;

    hipMemsetAsync(d_out, 0, (size_t)N_GRAPHS * DIM * sizeof(float), stream);

    init_deg_k<<<(N + 255) / 256, 256, 0, stream>>>(deg, N);
    count_k<<<(E + 255) / 256, 256, 0, stream>>>(dst, deg, E);
    dis_k<<<(N + 255) / 256, 256, 0, stream>>>(deg, dis, N);
    scan_k<<<1, 1024, 0, stream>>>(deg, row_ptr, N);
    cursor_k<<<(N + 255) / 256, 256, 0, stream>>>(row_ptr, cursor, N);
    fill_k<<<(E + N + 255) / 256, 256, 0, stream>>>(src, dst, dis, cursor, col, wgt, E, N);

    int gemm_grid = (N + GEMM_ROWS - 1) / GEMM_ROWS;
    int agg_grid  = (N + 3) / 4;

    gemm_k<<<gemm_grid, 256, 0, stream>>>(x,  W1, B1, N);
    agg_k<<<agg_grid, 256, 0, stream>>>(B1, row_ptr, col, wgt, b1, B2, N);

    gemm_k<<<gemm_grid, 256, 0, stream>>>(B2, W2, B1, N);
    agg_k<<<agg_grid, 256, 0, stream>>>(B1, row_ptr, col, wgt, b2, B2, N);

    gemm_k<<<gemm_grid, 256, 0, stream>>>(B2, W3, B1, N);
    agg_k<<<agg_grid, 256, 0, stream>>>(B1, row_ptr, col, wgt, b3, B2, N);

    pool_k<<<(N + 63) / 64, 128, 0, stream>>>(B2, bv, out, N);
}

// Round 2
// 564.521 us; speedup vs baseline: 1.1308x; 1.1308x over previous
//
#include <hip/hip_runtime.h>

#define N_NODES 50000
#define N_EDGES 800000
#define N_GRAPHS 512
#define DIM 128

// ---------------- graph preprocessing ----------------

__global__ void init_deg_k(int* deg, int n) {
    int i = blockIdx.x * blockDim.x + threadIdx.x;
    if (i < n) deg[i] = 1;  // self-loop
}

__global__ void count_k(const int* __restrict__ dst, int* deg, int e) {
    int i = blockIdx.x * blockDim.x + threadIdx.x;
    if (i < e) atomicAdd(&deg[dst[i]], 1);
}

__global__ void dis_k(const int* __restrict__ deg, float* dis, int n) {
    int i = blockIdx.x * blockDim.x + threadIdx.x;
    if (i < n) dis[i] = rsqrtf((float)deg[i]);   // deg >= 1 always (self-loops)
}

// ---------------- multi-block exclusive scan (3 phases) ----------------
// phase 1: per-block (2048 elems) local exclusive scan + block total
#define SCAN_TPB 256
#define SCAN_ELEMS 2048
#define SCAN_BLOCKS ((N_NODES + SCAN_ELEMS - 1) / SCAN_ELEMS)   // 25

__global__ __launch_bounds__(SCAN_TPB) void scan1_k(const int* __restrict__ deg,
                                                    int* __restrict__ local,
                                                    int* __restrict__ partials, int n) {
    __shared__ int lds[SCAN_ELEMS];   // 8 KB
    __shared__ int sums[SCAN_TPB];
    int t = threadIdx.x;
    int base = blockIdx.x * SCAN_ELEMS;
#pragma unroll
    for (int i = 0; i < 8; i++) {
        int idx = base + t + i * SCAN_TPB;           // coalesced
        lds[t + i * SCAN_TPB] = (idx < n) ? deg[idx] : 0;
    }
    __syncthreads();
    int off = t * 8;
    int s = 0;
#pragma unroll
    for (int i = 0; i < 8; i++) s += lds[off + i];
    sums[t] = s;
    __syncthreads();
    for (int o = 1; o < SCAN_TPB; o <<= 1) {
        int v = sums[t];
        int add = (t >= o) ? sums[t - o] : 0;
        __syncthreads();
        sums[t] = v + add;
        __syncthreads();
    }
    int run = (t == 0) ? 0 : sums[t - 1];
#pragma unroll
    for (int i = 0; i < 8; i++) {
        int v = lds[off + i];
        lds[off + i] = run;     // in-place: value -> exclusive prefix
        run += v;
    }
    if (t == SCAN_TPB - 1) partials[blockIdx.x] = run;   // block total
    __syncthreads();
#pragma unroll
    for (int i = 0; i < 8; i++) {
        int idx = base + t + i * SCAN_TPB;               // coalesced store
        if (idx < n) local[idx] = lds[t + i * SCAN_TPB];
    }
}

// phase 2: exclusive scan of the 25 block totals (trivial)
__global__ void scan2_k(int* partials) {
    if (threadIdx.x == 0) {
        int run = 0;
        for (int b = 0; b < SCAN_BLOCKS; b++) {
            int v = partials[b];
            partials[b] = run;
            run += v;
        }
    }
}

// phase 3: add block offsets; also produce cursor copy and row_ptr[n]
__global__ void scan3_k(int* __restrict__ row_ptr, const int* __restrict__ partials,
                        int* __restrict__ cursor, int n, int total) {
    int i = blockIdx.x * blockDim.x + threadIdx.x;
    if (i < n) {
        int r = row_ptr[i] + partials[i / SCAN_ELEMS];
        row_ptr[i] = r;
        cursor[i] = r;
    }
    if (i == 0) row_ptr[n] = total;
}

__global__ void fill_k(const int* __restrict__ src, const int* __restrict__ dst,
                       const float* __restrict__ dis, int* cursor,
                       int* col, float* wgt, int e, int n) {
    int i = blockIdx.x * blockDim.x + threadIdx.x;
    if (i < e) {
        int s = src[i], d = dst[i];
        int pos = atomicAdd(&cursor[d], 1);
        col[pos] = s;
        wgt[pos] = dis[s] * dis[d];
    } else if (i < e + n) {
        int v = i - e;
        int pos = atomicAdd(&cursor[v], 1);
        col[pos] = v;
        wgt[pos] = dis[v] * dis[v];
    }
}

// ---------------- dense GEMM: H[n x 128] = X[n x 128] @ W[128 x 128] ----------------

#define GEMM_ROWS 32

__global__ __launch_bounds__(256) void gemm_k(const float* __restrict__ X,
                                              const float* __restrict__ W,
                                              float* __restrict__ H, int n) {
    __shared__ float Ws[64 * 128];          // 32 KB (half of W's K range)
    __shared__ float Xs[GEMM_ROWS * 128];   // 16 KB

    int t = threadIdx.x;
    int row0 = blockIdx.x * GEMM_ROWS;

    for (int i = t; i < GEMM_ROWS * 32; i += 256) {
        int r = i >> 5, q = i & 31;
        float4 v = make_float4(0.f, 0.f, 0.f, 0.f);
        if (row0 + r < n) v = ((const float4*)X)[(size_t)(row0 + r) * 32 + q];
        ((float4*)Xs)[i] = v;
    }

    int tc = t & 31, tr = t >> 5;
    int j0 = tc * 4, r0 = tr * 4;
    float acc[4][4];
#pragma unroll
    for (int a = 0; a < 4; a++)
#pragma unroll
        for (int b = 0; b < 4; b++) acc[a][b] = 0.f;

    for (int kp = 0; kp < 2; kp++) {
        int k0 = kp * 64;
        __syncthreads();
        for (int i = t; i < 64 * 32; i += 256)
            ((float4*)Ws)[i] = ((const float4*)W)[k0 * 32 + i];
        __syncthreads();
#pragma unroll 4
        for (int k = 0; k < 64; k++) {
            float4 wv = *(const float4*)(Ws + k * 128 + j0);
#pragma unroll
            for (int a = 0; a < 4; a++) {
                float xv = Xs[(r0 + a) * 128 + k0 + k];
                acc[a][0] += xv * wv.x;
                acc[a][1] += xv * wv.y;
                acc[a][2] += xv * wv.z;
                acc[a][3] += xv * wv.w;
            }
        }
    }

#pragma unroll
    for (int a = 0; a < 4; a++) {
        int row = row0 + r0 + a;
        if (row < n)
            *(float4*)(H + (size_t)row * 128 + j0) =
                make_float4(acc[a][0], acc[a][1], acc[a][2], acc[a][3]);
    }
}

// ---------------- CSR aggregation + bias + ReLU ----------------

__global__ __launch_bounds__(256) void agg_k(const float* __restrict__ H,
                                             const int* __restrict__ row_ptr,
                                             const int* __restrict__ col,
                                             const float* __restrict__ wgt,
                                             const float* __restrict__ bias,
                                             float* __restrict__ Out, int n) {
    int node = blockIdx.x * 4 + (threadIdx.x >> 6);
    int lane = threadIdx.x & 63;
    if (node >= n) return;
    int beg = row_ptr[node], end = row_ptr[node + 1];
    float a0 = 0.f, a1 = 0.f;
    for (int e = beg; e < end; e++) {
        int c = col[e];
        float w = wgt[e];
        float2 hv = *(const float2*)(H + (size_t)c * DIM + lane * 2);
        a0 += w * hv.x;
        a1 += w * hv.y;
    }
    a0 += bias[lane * 2];
    a1 += bias[lane * 2 + 1];
    a0 = fmaxf(a0, 0.f);
    a1 = fmaxf(a1, 0.f);
    *(float2*)(Out + (size_t)node * DIM + lane * 2) = make_float2(a0, a1);
}

// ---------------- global add pool (batch_vec sorted) ----------------

__global__ void pool_k(const float* __restrict__ H, const int* __restrict__ batch,
                       float* Out, int n) {
    int d = threadIdx.x;
    int n0 = blockIdx.x * 64;
    int gcur = -1;
    float s = 0.f;
    for (int i = 0; i < 64; i++) {
        int node = n0 + i;
        if (node >= n) break;
        int g = batch[node];
        if (g != gcur) {
            if (gcur >= 0) atomicAdd(&Out[gcur * DIM + d], s);
            gcur = g;
            s = 0.f;
        }
        s += H[(size_t)node * DIM + d];
    }
    if (gcur >= 0) atomicAdd(&Out[gcur * DIM + d], s);
}

// ---------------- launch ----------------

extern "C" void kernel_launch(void* const* d_in, const int* in_sizes, int n_in,
                              void* d_out, int out_size, void* d_ws, size_t ws_size,
                              hipStream_t stream) {
    const float* x  = (const float*)d_in[0];
    const float* W1 = (const float*)d_in[1];
    const float* b1 = (const float*)d_in[2];
    const float* W2 = (const float*)d_in[3];
    const float* b2 = (const float*)d_in[4];
    const float* W3 = (const float*)d_in[5];
    const float* b3 = (const float*)d_in[6];
    const int*   ei = (const int*)d_in[7];     // [2, E] flat
    const int*   bv = (const int*)d_in[8];     // [N], sorted
    float* out = (float*)d_out;

    const int N = N_NODES, E = N_EDGES;

    char* p = (char*)d_ws;
    auto alloc = [&](size_t bytes) -> void* {
        void* r = (void*)p;
        p += (bytes + 255) & ~(size_t)255;
        return r;
    };
    int*   deg      = (int*)alloc((size_t)N * 4);
    int*   row_ptr  = (int*)alloc((size_t)(N + 1) * 4);
    int*   cursor   = (int*)alloc((size_t)N * 4);
    int*   partials = (int*)alloc((size_t)SCAN_BLOCKS * 4);
    float* dis      = (float*)alloc((size_t)N * 4);
    int*   col      = (int*)alloc((size_t)(E + N) * 4);
    float* wgt      = (float*)alloc((size_t)(E + N) * 4);
    float* B1       = (float*)alloc((size_t)N * DIM * 4);
    float* B2       = (float*)alloc((size_t)N * DIM * 4);

    const int* src = ei;
    const int* dst = ei + E;

    hipMemsetAsync(d_out, 0, (size_t)N_GRAPHS * DIM * sizeof(float), stream);

    init_deg_k<<<(N + 255) / 256, 256, 0, stream>>>(deg, N);
    count_k<<<(E + 255) / 256, 256, 0, stream>>>(dst, deg, E);
    dis_k<<<(N + 255) / 256, 256, 0, stream>>>(deg, dis, N);
    scan1_k<<<SCAN_BLOCKS, SCAN_TPB, 0, stream>>>(deg, row_ptr, partials, N);
    scan2_k<<<1, 64, 0, stream>>>(partials);
    scan3_k<<<(N + 255) / 256, 256, 0, stream>>>(row_ptr, partials, cursor, N, E + N);
    fill_k<<<(E + N + 255) / 256, 256, 0, stream>>>(src, dst, dis, cursor, col, wgt, E, N);

    int gemm_grid = (N + GEMM_ROWS - 1) / GEMM_ROWS;
    int agg_grid  = (N + 3) / 4;

    gemm_k<<<gemm_grid, 256, 0, stream>>>(x,  W1, B1, N);
    agg_k<<<agg_grid, 256, 0, stream>>>(B1, row_ptr, col, wgt, b1, B2, N);

    gemm_k<<<gemm_grid, 256, 0, stream>>>(B2, W2, B1, N);
    agg_k<<<agg_grid, 256, 0, stream>>>(B1, row_ptr, col, wgt, b2, B2, N);

    gemm_k<<<gemm_grid, 256, 0, stream>>>(B2, W3, B1, N);
    agg_k<<<agg_grid, 256, 0, stream>>>(B1, row_ptr, col, wgt, b3, B2, N);

    pool_k<<<(N + 63) / 64, 128, 0, stream>>>(B2, bv, out, N);
}

// Round 3
// 402.943 us; speedup vs baseline: 1.5843x; 1.4010x over previous
//
#include <hip/hip_runtime.h>

#define N_NODES 50000
#define N_EDGES 800000
#define N_GRAPHS 512
#define DIM 128

typedef unsigned int uint;
typedef unsigned short ushort;

// bf16 helpers (RNE pack, cheap unpack)
__device__ __forceinline__ ushort f2bf(float f) {
    uint u = __float_as_uint(f);
    return (ushort)((u + 0x7fffu + ((u >> 16) & 1u)) >> 16);
}
__device__ __forceinline__ float bflo(uint p) { return __uint_as_float(p << 16); }
__device__ __forceinline__ float bfhi(uint p) { return __uint_as_float(p & 0xffff0000u); }

// ---------------- graph preprocessing ----------------

__global__ void init_deg_k(int* deg, int n) {
    int i = blockIdx.x * blockDim.x + threadIdx.x;
    if (i < n) deg[i] = 1;  // self-loop
}

__global__ void count_k(const int* __restrict__ dst, int* deg, int e) {
    int i = blockIdx.x * blockDim.x + threadIdx.x;
    if (i < e) atomicAdd(&deg[dst[i]], 1);
}

__global__ void dis_k(const int* __restrict__ deg, float* dis, int n) {
    int i = blockIdx.x * blockDim.x + threadIdx.x;
    if (i < n) dis[i] = rsqrtf((float)deg[i]);
}

// ---------------- multi-block exclusive scan (3 phases) ----------------
#define SCAN_TPB 256
#define SCAN_ELEMS 2048
#define SCAN_BLOCKS ((N_NODES + SCAN_ELEMS - 1) / SCAN_ELEMS)   // 25

__global__ __launch_bounds__(SCAN_TPB) void scan1_k(const int* __restrict__ deg,
                                                    int* __restrict__ local,
                                                    int* __restrict__ partials, int n) {
    __shared__ int lds[SCAN_ELEMS];
    __shared__ int sums[SCAN_TPB];
    int t = threadIdx.x;
    int base = blockIdx.x * SCAN_ELEMS;
#pragma unroll
    for (int i = 0; i < 8; i++) {
        int idx = base + t + i * SCAN_TPB;
        lds[t + i * SCAN_TPB] = (idx < n) ? deg[idx] : 0;
    }
    __syncthreads();
    int off = t * 8;
    int s = 0;
#pragma unroll
    for (int i = 0; i < 8; i++) s += lds[off + i];
    sums[t] = s;
    __syncthreads();
    for (int o = 1; o < SCAN_TPB; o <<= 1) {
        int v = sums[t];
        int add = (t >= o) ? sums[t - o] : 0;
        __syncthreads();
        sums[t] = v + add;
        __syncthreads();
    }
    int run = (t == 0) ? 0 : sums[t - 1];
#pragma unroll
    for (int i = 0; i < 8; i++) {
        int v = lds[off + i];
        lds[off + i] = run;
        run += v;
    }
    if (t == SCAN_TPB - 1) partials[blockIdx.x] = run;
    __syncthreads();
#pragma unroll
    for (int i = 0; i < 8; i++) {
        int idx = base + t + i * SCAN_TPB;
        if (idx < n) local[idx] = lds[t + i * SCAN_TPB];
    }
}

__global__ void scan2_k(int* partials) {
    if (threadIdx.x == 0) {
        int run = 0;
        for (int b = 0; b < SCAN_BLOCKS; b++) {
            int v = partials[b];
            partials[b] = run;
            run += v;
        }
    }
}

__global__ void scan3_k(int* __restrict__ row_ptr, const int* __restrict__ partials,
                        int* __restrict__ cursor, int n, int total) {
    int i = blockIdx.x * blockDim.x + threadIdx.x;
    if (i < n) {
        int r = row_ptr[i] + partials[i / SCAN_ELEMS];
        row_ptr[i] = r;
        cursor[i] = r;
    }
    if (i == 0) row_ptr[n] = total;
}

__global__ void fill_k(const int* __restrict__ src, const int* __restrict__ dst,
                       const float* __restrict__ dis, int* cursor,
                       int* col, float* wgt, int e, int n) {
    int i = blockIdx.x * blockDim.x + threadIdx.x;
    if (i < e) {
        int s = src[i], d = dst[i];
        int pos = atomicAdd(&cursor[d], 1);
        col[pos] = s;
        wgt[pos] = dis[s] * dis[d];
    } else if (i < e + n) {
        int v = i - e;
        int pos = atomicAdd(&cursor[v], 1);
        col[pos] = v;
        wgt[pos] = dis[v] * dis[v];
    }
}

// ---------------- dense GEMM: H[n x 128](bf16) = X[n x 128] @ W[128 x 128] ----------------
// TIn = float (layer 1) or ushort/bf16 (layers 2,3). fp32 accumulate, bf16 store.

#define GEMM_ROWS 32

template <typename TIn>
__global__ __launch_bounds__(256) void gemm_k(const TIn* __restrict__ X,
                                              const float* __restrict__ W,
                                              ushort* __restrict__ H, int n) {
    __shared__ float Ws[64 * 128];          // 32 KB
    __shared__ float Xs[GEMM_ROWS * 128];   // 16 KB

    int t = threadIdx.x;
    int row0 = blockIdx.x * GEMM_ROWS;

    // stage X tile as fp32 (4 elems per i); both paths index chunk (row*32 + q)
    for (int i = t; i < GEMM_ROWS * 32; i += 256) {
        int r = i >> 5, q = i & 31;
        float4 v = make_float4(0.f, 0.f, 0.f, 0.f);
        if (row0 + r < n) {
            if constexpr (sizeof(TIn) == 4) {
                v = ((const float4*)X)[(size_t)(row0 + r) * 32 + q];
            } else {
                uint2 p = ((const uint2*)X)[(size_t)(row0 + r) * 32 + q];
                v = make_float4(bflo(p.x), bfhi(p.x), bflo(p.y), bfhi(p.y));
            }
        }
        ((float4*)Xs)[i] = v;
    }

    int tc = t & 31, tr = t >> 5;
    int j0 = tc * 4, r0 = tr * 4;
    float acc[4][4];
#pragma unroll
    for (int a = 0; a < 4; a++)
#pragma unroll
        for (int b = 0; b < 4; b++) acc[a][b] = 0.f;

    for (int kp = 0; kp < 2; kp++) {
        int k0 = kp * 64;
        __syncthreads();
        for (int i = t; i < 64 * 32; i += 256)
            ((float4*)Ws)[i] = ((const float4*)W)[k0 * 32 + i];
        __syncthreads();
#pragma unroll 4
        for (int k = 0; k < 64; k++) {
            float4 wv = *(const float4*)(Ws + k * 128 + j0);
#pragma unroll
            for (int a = 0; a < 4; a++) {
                float xv = Xs[(r0 + a) * 128 + k0 + k];
                acc[a][0] += xv * wv.x;
                acc[a][1] += xv * wv.y;
                acc[a][2] += xv * wv.z;
                acc[a][3] += xv * wv.w;
            }
        }
    }

#pragma unroll
    for (int a = 0; a < 4; a++) {
        int row = row0 + r0 + a;
        if (row < n) {
            uint o0 = (uint)f2bf(acc[a][0]) | ((uint)f2bf(acc[a][1]) << 16);
            uint o1 = (uint)f2bf(acc[a][2]) | ((uint)f2bf(acc[a][3]) << 16);
            *(uint2*)(H + (size_t)row * DIM + j0) = make_uint2(o0, o1);
        }
    }
}

// ---------------- CSR aggregation + bias + ReLU (bf16 in/out, fp32 accum) ----------------
// 2 nodes per wave (32 lanes x uint2 = 256B row), 4-edge unroll for MLP.

__global__ __launch_bounds__(256) void agg_k(const ushort* __restrict__ H,
                                             const int* __restrict__ row_ptr,
                                             const int* __restrict__ col,
                                             const float* __restrict__ wgt,
                                             const float* __restrict__ bias,
                                             ushort* __restrict__ Out, int n) {
    int node = blockIdx.x * 8 + (threadIdx.x >> 5);
    int lane = threadIdx.x & 31;        // 32 lanes per node, 4 features/lane
    if (node >= n) return;
    int beg = row_ptr[node], end = row_ptr[node + 1];
    float a0 = 0.f, a1 = 0.f, a2 = 0.f, a3 = 0.f;
    int e = beg;
    for (; e + 3 < end; e += 4) {
        int c0 = col[e], c1 = col[e + 1], c2 = col[e + 2], c3 = col[e + 3];
        float w0 = wgt[e], w1 = wgt[e + 1], w2 = wgt[e + 2], w3 = wgt[e + 3];
        uint2 p0 = *(const uint2*)(H + (size_t)c0 * DIM + lane * 4);
        uint2 p1 = *(const uint2*)(H + (size_t)c1 * DIM + lane * 4);
        uint2 p2 = *(const uint2*)(H + (size_t)c2 * DIM + lane * 4);
        uint2 p3 = *(const uint2*)(H + (size_t)c3 * DIM + lane * 4);
        a0 += w0 * bflo(p0.x) + w1 * bflo(p1.x) + w2 * bflo(p2.x) + w3 * bflo(p3.x);
        a1 += w0 * bfhi(p0.x) + w1 * bfhi(p1.x) + w2 * bfhi(p2.x) + w3 * bfhi(p3.x);
        a2 += w0 * bflo(p0.y) + w1 * bflo(p1.y) + w2 * bflo(p2.y) + w3 * bflo(p3.y);
        a3 += w0 * bfhi(p0.y) + w1 * bfhi(p1.y) + w2 * bfhi(p2.y) + w3 * bfhi(p3.y);
    }
    for (; e < end; e++) {
        int c = col[e];
        float w = wgt[e];
        uint2 p = *(const uint2*)(H + (size_t)c * DIM + lane * 4);
        a0 += w * bflo(p.x);
        a1 += w * bfhi(p.x);
        a2 += w * bflo(p.y);
        a3 += w * bfhi(p.y);
    }
    int d0 = lane * 4;
    a0 = fmaxf(a0 + bias[d0], 0.f);
    a1 = fmaxf(a1 + bias[d0 + 1], 0.f);
    a2 = fmaxf(a2 + bias[d0 + 2], 0.f);
    a3 = fmaxf(a3 + bias[d0 + 3], 0.f);
    uint o0 = (uint)f2bf(a0) | ((uint)f2bf(a1) << 16);
    uint o1 = (uint)f2bf(a2) | ((uint)f2bf(a3) << 16);
    *(uint2*)(Out + (size_t)node * DIM + d0) = make_uint2(o0, o1);
}

// ---------------- global add pool (batch_vec sorted, bf16 in, fp32 out) ----------------

__global__ void pool_k(const ushort* __restrict__ H, const int* __restrict__ batch,
                       float* Out, int n) {
    int d = threadIdx.x;
    int n0 = blockIdx.x * 64;
    int gcur = -1;
    float s = 0.f;
    for (int i = 0; i < 64; i++) {
        int node = n0 + i;
        if (node >= n) break;
        int g = batch[node];
        if (g != gcur) {
            if (gcur >= 0) atomicAdd(&Out[gcur * DIM + d], s);
            gcur = g;
            s = 0.f;
        }
        s += bflo((uint)H[(size_t)node * DIM + d]);
    }
    if (gcur >= 0) atomicAdd(&Out[gcur * DIM + d], s);
}

// ---------------- launch ----------------

extern "C" void kernel_launch(void* const* d_in, const int* in_sizes, int n_in,
                              void* d_out, int out_size, void* d_ws, size_t ws_size,
                              hipStream_t stream) {
    const float* x  = (const float*)d_in[0];
    const float* W1 = (const float*)d_in[1];
    const float* b1 = (const float*)d_in[2];
    const float* W2 = (const float*)d_in[3];
    const float* b2 = (const float*)d_in[4];
    const float* W3 = (const float*)d_in[5];
    const float* b3 = (const float*)d_in[6];
    const int*   ei = (const int*)d_in[7];
    const int*   bv = (const int*)d_in[8];
    float* out = (float*)d_out;

    const int N = N_NODES, E = N_EDGES;

    char* p = (char*)d_ws;
    auto alloc = [&](size_t bytes) -> void* {
        void* r = (void*)p;
        p += (bytes + 255) & ~(size_t)255;
        return r;
    };
    int*    deg      = (int*)alloc((size_t)N * 4);
    int*    row_ptr  = (int*)alloc((size_t)(N + 1) * 4);
    int*    cursor   = (int*)alloc((size_t)N * 4);
    int*    partials = (int*)alloc((size_t)SCAN_BLOCKS * 4);
    float*  dis      = (float*)alloc((size_t)N * 4);
    int*    col      = (int*)alloc((size_t)(E + N) * 4);
    float*  wgt      = (float*)alloc((size_t)(E + N) * 4);
    ushort* B1       = (ushort*)alloc((size_t)N * DIM * 2);
    ushort* B2       = (ushort*)alloc((size_t)N * DIM * 2);

    const int* src = ei;
    const int* dst = ei + E;

    hipMemsetAsync(d_out, 0, (size_t)N_GRAPHS * DIM * sizeof(float), stream);

    init_deg_k<<<(N + 255) / 256, 256, 0, stream>>>(deg, N);
    count_k<<<(E + 255) / 256, 256, 0, stream>>>(dst, deg, E);
    dis_k<<<(N + 255) / 256, 256, 0, stream>>>(deg, dis, N);
    scan1_k<<<SCAN_BLOCKS, SCAN_TPB, 0, stream>>>(deg, row_ptr, partials, N);
    scan2_k<<<1, 64, 0, stream>>>(partials);
    scan3_k<<<(N + 255) / 256, 256, 0, stream>>>(row_ptr, partials, cursor, N, E + N);
    fill_k<<<(E + N + 255) / 256, 256, 0, stream>>>(src, dst, dis, cursor, col, wgt, E, N);

    int gemm_grid = (N + GEMM_ROWS - 1) / GEMM_ROWS;
    int agg_grid  = (N + 7) / 8;

    gemm_k<float><<<gemm_grid, 256, 0, stream>>>(x,  W1, B1, N);
    agg_k<<<agg_grid, 256, 0, stream>>>(B1, row_ptr, col, wgt, b1, B2, N);

    gemm_k<ushort><<<gemm_grid, 256, 0, stream>>>(B2, W2, B1, N);
    agg_k<<<agg_grid, 256, 0, stream>>>(B1, row_ptr, col, wgt, b2, B2, N);

    gemm_k<ushort><<<gemm_grid, 256, 0, stream>>>(B2, W3, B1, N);
    agg_k<<<agg_grid, 256, 0, stream>>>(B1, row_ptr, col, wgt, b3, B2, N);

    pool_k<<<(N + 63) / 64, 128, 0, stream>>>(B2, bv, out, N);
}